// Round 3
// baseline (439.457 us; speedup 1.0000x reference)
//
#include <hip/hip_runtime.h>

typedef _Float16 f16;
typedef _Float16 half8 __attribute__((ext_vector_type(8)));
typedef _Float16 half4v __attribute__((ext_vector_type(4)));
typedef __fp16 fp16x2 __attribute__((ext_vector_type(2)));
typedef float floatx4 __attribute__((ext_vector_type(4)));
typedef unsigned int uint;

constexpr int Bsz = 4, Tseq = 2048, Cdim = 1024, NH = 16, HDim = 64;
constexpr int Mtok = Bsz * Tseq;      // 8192
constexpr int N_QKV = 3 * Cdim;       // 3072
constexpr int NQT = Tseq / 64;        // 32 q-tiles
constexpr float QSCALE = 0.18033688f; // 0.125 * log2(e)

#define GLDS16(src, dst) __builtin_amdgcn_global_load_lds( \
    (const __attribute__((address_space(1))) void*)(src),  \
    (__attribute__((address_space(3))) void*)(dst), 16, 0, 0)

__device__ __forceinline__ float fexp2(float x) { return __builtin_amdgcn_exp2f(x); }
__device__ __forceinline__ uint pkrtz(float a, float b) {
  fp16x2 h = __builtin_amdgcn_cvt_pkrtz(a, b);
  return __builtin_bit_cast(uint, h);
}

// ---------------- f32 -> f16 conversion ----------------
__global__ void cvt_kernel(const float* __restrict__ in, f16* __restrict__ out, int n) {
  int i = (blockIdx.x * blockDim.x + threadIdx.x) * 4;
  if (i >= n) return;
  float4 v = *(const float4*)(in + i);
  half4v o;
  o[0] = (f16)v.x; o[1] = (f16)v.y; o[2] = (f16)v.z; o[3] = (f16)v.w;
  *(half4v*)(out + i) = o;
}

// ---------------- GEMM: C[m][n] = sum_k X[m][k] * W[n][k] ----------------
template<int EPI>
__global__ __launch_bounds__(256)
void gemm_kernel(const f16* __restrict__ X, const f16* __restrict__ W,
                 float* __restrict__ outF,
                 f16* __restrict__ q_out, f16* __restrict__ k_out, f16* __restrict__ v_out,
                 int M, int N, int K)
{
  constexpr int BM = 128, BN = 128, BK = 32;
  __shared__ __align__(16) f16 As[BM * BK];
  __shared__ __align__(16) f16 Bs[BN * BK];
  const int tid = threadIdx.x;
  const int wave = tid >> 6;
  const int lane = tid & 63;
  const int g = lane >> 4, lm = lane & 15;
  const int nbn = N / BN;
  const int bm = blockIdx.x / nbn;
  const int bn = blockIdx.x % nbn;
  const int m0 = bm * BM, n0 = bn * BN;
  const int wr = wave >> 1, wc = wave & 1;

  floatx4 acc[4][4];
#pragma unroll
  for (int i = 0; i < 4; ++i)
#pragma unroll
    for (int j = 0; j < 4; ++j) acc[i][j] = (floatx4)0.0f;

  for (int k0 = 0; k0 < K; k0 += BK) {
    __syncthreads();
#pragma unroll
    for (int t = 0; t < 2; ++t) {
      int row = (wave * 2 + t) * 16 + (lane >> 2);
      int cg = (lane & 3) ^ ((row >> 1) & 3);
      const f16* srcA = X + (size_t)(m0 + row) * K + k0 + cg * 8;
      GLDS16(srcA, (char*)As + (wave * 2 + t) * 1024);
      const f16* srcB = W + (size_t)(n0 + row) * K + k0 + cg * 8;
      GLDS16(srcB, (char*)Bs + (wave * 2 + t) * 1024);
    }
    __syncthreads();

    half8 af[4], bf[4];
#pragma unroll
    for (int i = 0; i < 4; ++i) {
      int rowa = wr * 64 + i * 16 + lm;
      int cga = g ^ ((rowa >> 1) & 3);
      af[i] = *(const half8*)((const char*)As + rowa * 64 + cga * 16);
      int rowb = wc * 64 + i * 16 + lm;
      int cgb = g ^ ((rowb >> 1) & 3);
      bf[i] = *(const half8*)((const char*)Bs + rowb * 64 + cgb * 16);
    }
#pragma unroll
    for (int i = 0; i < 4; ++i)
#pragma unroll
      for (int j = 0; j < 4; ++j)
        acc[i][j] = __builtin_amdgcn_mfma_f32_16x16x32_f16(af[i], bf[j], acc[i][j], 0, 0, 0);
  }

#pragma unroll
  for (int i = 0; i < 4; ++i) {
#pragma unroll
    for (int j = 0; j < 4; ++j) {
#pragma unroll
      for (int r = 0; r < 4; ++r) {
        int m = m0 + wr * 64 + i * 16 + 4 * g + r;
        int n = n0 + wc * 64 + j * 16 + lm;
        float v = acc[i][j][r];
        if constexpr (EPI == 1) {
          outF[(size_t)m * N + n] = v;
        } else {
          int which = n >> 10;
          int inner = n & 1023;
          int h = inner >> 6, hd = inner & 63;
          int b = m >> 11, t = m & 2047;
          if (which == 0) v *= QSCALE;  // fold softmax scale*log2e into Q
          f16* dst = which == 0 ? q_out : (which == 1 ? k_out : v_out);
          dst[(((size_t)(b * NH + h)) * Tseq + t) * HDim + hd] = (f16)v;
        }
      }
    }
  }
}

// ---------------- causal flash attention, paired q-tiles ----------------
__device__ __forceinline__ void commit_kv(char* kb, char* vbuf, int kr, int kc, int vkv, int vh0,
                                          half8 k0, half8 k1, half8 v0, half8 v1) {
  *(half8*)(kb + kr * 128 + 16 * ((2 * kc)     ^ (kr & 7))) = k0;
  *(half8*)(kb + kr * 128 + 16 * ((2 * kc + 1) ^ (kr & 7))) = k1;
#pragma unroll
  for (int i = 0; i < 8; ++i) {
    *(f16*)(vbuf + (vh0 + i)     * 128 + 16 * ((vkv >> 3) ^ i) + (vkv & 7) * 2) = v0[i];
    *(f16*)(vbuf + (vh0 + 8 + i) * 128 + 16 * ((vkv >> 3) ^ i) + (vkv & 7) * 2) = v1[i];
  }
}

__device__ __forceinline__ void softmax_tile(floatx4* s, float& m_run, float& l_run, floatx4* acc,
                                             bool diag, int j0, int qg, char* pwrow, int g, int lm) {
  if (diag) {
#pragma unroll
    for (int nf = 0; nf < 4; ++nf)
#pragma unroll
      for (int r = 0; r < 4; ++r)
        if (j0 + nf * 16 + 4 * g + r > qg) s[nf][r] = -1e30f;
  }
  float mx = -1e30f;
#pragma unroll
  for (int nf = 0; nf < 4; ++nf) {
    float a = fmaxf(fmaxf(s[nf][0], s[nf][1]), fmaxf(s[nf][2], s[nf][3]));
    mx = fmaxf(mx, a);
  }
  mx = fmaxf(mx, __shfl_xor(mx, 16, 64));
  mx = fmaxf(mx, __shfl_xor(mx, 32, 64));
  if (!__all(mx <= m_run + 8.0f)) {   // defer-max (T13)
    float nm = fmaxf(m_run, mx);
    float sc = fexp2(m_run - nm);
    m_run = nm;
    l_run *= sc;
    float s0 = __shfl(sc, 4 * g + 0, 64), s1 = __shfl(sc, 4 * g + 1, 64);
    float s2 = __shfl(sc, 4 * g + 2, 64), s3 = __shfl(sc, 4 * g + 3, 64);
#pragma unroll
    for (int ng = 0; ng < 4; ++ng) {
      acc[ng][0] *= s0; acc[ng][1] *= s1; acc[ng][2] *= s2; acc[ng][3] *= s3;
    }
  }
  float rs = 0.f;
#pragma unroll
  for (int nf = 0; nf < 4; ++nf) {
    float p0 = fexp2(s[nf][0] - m_run), p1 = fexp2(s[nf][1] - m_run);
    float p2 = fexp2(s[nf][2] - m_run), p3 = fexp2(s[nf][3] - m_run);
    rs += (p0 + p1) + (p2 + p3);
    uint lo = pkrtz(p0, p1), hi = pkrtz(p2, p3);
    int slot = 2 * nf + (g >> 1);
    uint2 u; u.x = lo; u.y = hi;
    *(uint2*)(pwrow + 16 * (slot ^ (lm & 7)) + 8 * (g & 1)) = u;
  }
  rs += __shfl_xor(rs, 16, 64);
  rs += __shfl_xor(rs, 32, 64);
  l_run += rs;
}

__device__ __forceinline__ void store_o(const floatx4* acc, float l, int q0w, int g, int lm,
                                        f16* __restrict__ Y, int b, int h) {
#pragma unroll
  for (int r = 0; r < 4; ++r) {
    float lq = __shfl(l, 4 * g + r, 64);
    float inv = 1.0f / lq;
    int t = q0w + 4 * g + r;
    size_t base = ((size_t)(b * Tseq + t)) * Cdim + h * HDim;
#pragma unroll
    for (int ng = 0; ng < 4; ++ng)
      Y[base + ng * 16 + lm] = (f16)(acc[ng][r] * inv);
  }
}

__global__ __launch_bounds__(256, 4)
void attn_kernel(const f16* __restrict__ Q, const f16* __restrict__ Kg,
                 const f16* __restrict__ V, f16* __restrict__ Y)
{
  // LDS: K dbuf 2*8192 | V dbuf 2*8192 | Pw 4 waves * 2048  == 40960 (4 blocks/CU exact)
  __shared__ __align__(16) char smem[40960];
  // XCD-locality remap: each XCD owns contiguous bh range
  int wg = blockIdx.x;
  int lin = (wg & 7) * 128 + (wg >> 3);
  const int p  = lin & 15;
  const int bh = lin >> 4;
  const int qtA = p, qtB = NQT - 1 - p;
  const int ntB = NQT - p;
  const f16* Qb = Q + (size_t)bh * Tseq * HDim;
  const f16* Kb = Kg + (size_t)bh * Tseq * HDim;
  const f16* Vb = V + (size_t)bh * Tseq * HDim;

  const int tid = threadIdx.x, w = tid >> 6, lane = tid & 63;
  const int g = lane >> 4, lm = lane & 15;
  char* pwrow = smem + 32768 + w * 2048 + lm * 128;

  const int q0A = qtA * 64, q0B = qtB * 64;
  const int qgA = q0A + w * 16 + lm, qgB = q0B + w * 16 + lm;

  half8 qfA0 = *(const half8*)(Qb + (size_t)(q0A + w * 16 + lm) * HDim + g * 8);
  half8 qfA1 = *(const half8*)(Qb + (size_t)(q0A + w * 16 + lm) * HDim + 32 + g * 8);
  half8 qfB0 = *(const half8*)(Qb + (size_t)(q0B + w * 16 + lm) * HDim + g * 8);
  half8 qfB1 = *(const half8*)(Qb + (size_t)(q0B + w * 16 + lm) * HDim + 32 + g * 8);

  floatx4 accA[4], accB[4];
  float mA = -1e30f, lA = 0.f, mB = -1e30f, lB = 0.f;
#pragma unroll
  for (int ng = 0; ng < 4; ++ng) { accA[ng] = (floatx4)0.f; accB[ng] = (floatx4)0.f; }

  const int kr = tid >> 2, kc = tid & 3;
  const int vkv = tid & 63, vh0 = (tid >> 6) * 16;

  { // prologue: stage tile 0 into buffer 0
    const f16* kg = Kb + (size_t)kr * HDim + kc * 16;
    half8 k0 = *(const half8*)kg, k1 = *(const half8*)(kg + 8);
    const f16* vg = Vb + (size_t)vkv * HDim + vh0;
    half8 v0 = *(const half8*)vg, v1 = *(const half8*)(vg + 8);
    commit_kv(smem, smem + 16384, kr, kc, vkv, vh0, k0, k1, v0, v1);
  }
  __syncthreads();

  for (int jt = 0; jt < ntB; ++jt) {
    const int cur = jt & 1;
    const int j0 = jt * 64;
    const bool activeA = (jt <= p);
    const bool more = (jt + 1 < ntB);
    half8 k0, k1, v0, v1;
    if (more) {  // T14: issue next tile's global loads before compute
      const f16* kg = Kb + (size_t)(j0 + 64 + kr) * HDim + kc * 16;
      k0 = *(const half8*)kg; k1 = *(const half8*)(kg + 8);
      const f16* vg = Vb + (size_t)(j0 + 64 + vkv) * HDim + vh0;
      v0 = *(const half8*)vg; v1 = *(const half8*)(vg + 8);
    }
    char* kb   = smem + cur * 8192;
    char* vbuf = smem + 16384 + cur * 8192;

    floatx4 sA[4], sB[4];
    if (activeA) {
#pragma unroll
      for (int nf = 0; nf < 4; ++nf) {
        half8 kf0 = *(const half8*)(kb + (nf * 16 + lm) * 128 + 16 * ((g)     ^ (lm & 7)));
        half8 kf1 = *(const half8*)(kb + (nf * 16 + lm) * 128 + 16 * ((4 + g) ^ (lm & 7)));
        sB[nf] = __builtin_amdgcn_mfma_f32_16x16x32_f16(kf0, qfB0, (floatx4)0.f, 0, 0, 0);
        sB[nf] = __builtin_amdgcn_mfma_f32_16x16x32_f16(kf1, qfB1, sB[nf], 0, 0, 0);
        sA[nf] = __builtin_amdgcn_mfma_f32_16x16x32_f16(kf0, qfA0, (floatx4)0.f, 0, 0, 0);
        sA[nf] = __builtin_amdgcn_mfma_f32_16x16x32_f16(kf1, qfA1, sA[nf], 0, 0, 0);
      }
    } else {
#pragma unroll
      for (int nf = 0; nf < 4; ++nf) {
        half8 kf0 = *(const half8*)(kb + (nf * 16 + lm) * 128 + 16 * ((g)     ^ (lm & 7)));
        half8 kf1 = *(const half8*)(kb + (nf * 16 + lm) * 128 + 16 * ((4 + g) ^ (lm & 7)));
        sB[nf] = __builtin_amdgcn_mfma_f32_16x16x32_f16(kf0, qfB0, (floatx4)0.f, 0, 0, 0);
        sB[nf] = __builtin_amdgcn_mfma_f32_16x16x32_f16(kf1, qfB1, sB[nf], 0, 0, 0);
      }
    }

    softmax_tile(sB, mB, lB, accB, jt == qtB, j0, qgB, pwrow, g, lm);
    half8 paB0 = *(const half8*)(pwrow + 16 * ((g)     ^ (lm & 7)));
    half8 paB1 = *(const half8*)(pwrow + 16 * ((4 + g) ^ (lm & 7)));
    half8 paA0 = paB0, paA1 = paB1;
    if (activeA) {
      softmax_tile(sA, mA, lA, accA, jt == qtA, j0, qgA, pwrow, g, lm);
      paA0 = *(const half8*)(pwrow + 16 * ((g)     ^ (lm & 7)));
      paA1 = *(const half8*)(pwrow + 16 * ((4 + g) ^ (lm & 7)));
    }

    if (activeA) {
#pragma unroll
      for (int c = 0; c < 2; ++c)
#pragma unroll
        for (int ng = 0; ng < 4; ++ng) {
          half8 vbf = *(const half8*)(vbuf + (ng * 16 + lm) * 128 + 16 * ((4 * c + g) ^ (lm & 7)));
          accB[ng] = __builtin_amdgcn_mfma_f32_16x16x32_f16(c ? paB1 : paB0, vbf, accB[ng], 0, 0, 0);
          accA[ng] = __builtin_amdgcn_mfma_f32_16x16x32_f16(c ? paA1 : paA0, vbf, accA[ng], 0, 0, 0);
        }
    } else {
#pragma unroll
      for (int c = 0; c < 2; ++c)
#pragma unroll
        for (int ng = 0; ng < 4; ++ng) {
          half8 vbf = *(const half8*)(vbuf + (ng * 16 + lm) * 128 + 16 * ((4 * c + g) ^ (lm & 7)));
          accB[ng] = __builtin_amdgcn_mfma_f32_16x16x32_f16(c ? paB1 : paB0, vbf, accB[ng], 0, 0, 0);
        }
    }

    if (more)
      commit_kv(smem + (cur ^ 1) * 8192, smem + 16384 + (cur ^ 1) * 8192,
                kr, kc, vkv, vh0, k0, k1, v0, v1);
    __syncthreads();
  }

  const int b = bh >> 4, h = bh & 15;
  store_o(accA, lA, q0A + 16 * w, g, lm, Y, b, h);
  store_o(accB, lB, q0B + 16 * w, g, lm, Y, b, h);
}

// ---------------- launcher ----------------
extern "C" void kernel_launch(void* const* d_in, const int* in_sizes, int n_in,
                              void* d_out, int out_size, void* d_ws, size_t ws_size,
                              hipStream_t stream)
{
  const float* x      = (const float*)d_in[0];
  const float* W_attn = (const float*)d_in[1];
  const float* W_proj = (const float*)d_in[2];
  float* out = (float*)d_out;

  char* ws = (char*)d_ws;
  f16* xh  = (f16*)(ws);
  f16* wAh = (f16*)(ws + (size_t)(16u << 20));
  f16* wPh = (f16*)(ws + (size_t)(22u << 20));
  f16* Qh  = (f16*)(ws + (size_t)(24u << 20));
  f16* Kh  = (f16*)(ws + (size_t)(40u << 20));
  f16* Vh  = (f16*)(ws + (size_t)(56u << 20));
  f16* yh  = xh;

  const int nx  = Mtok * Cdim;
  const int nwa = N_QKV * Cdim;
  const int nwp = Cdim * Cdim;
  cvt_kernel<<<(nx / 4 + 255) / 256, 256, 0, stream>>>(x, xh, nx);
  cvt_kernel<<<(nwa / 4 + 255) / 256, 256, 0, stream>>>(W_attn, wAh, nwa);
  cvt_kernel<<<(nwp / 4 + 255) / 256, 256, 0, stream>>>(W_proj, wPh, nwp);

  gemm_kernel<0><<<dim3((Mtok / 128) * (N_QKV / 128)), 256, 0, stream>>>(
      xh, wAh, nullptr, Qh, Kh, Vh, Mtok, N_QKV, Cdim);

  attn_kernel<<<dim3(1024), 256, 0, stream>>>(Qh, Kh, Vh, yh);

  gemm_kernel<1><<<dim3((Mtok / 128) * (Cdim / 128)), 256, 0, stream>>>(
      yh, wPh, out, nullptr, nullptr, nullptr, Mtok, Cdim, Cdim);
}

// Round 4
// 226.306 us; speedup vs baseline: 1.9419x; 1.9419x over previous
//
#include <hip/hip_runtime.h>

typedef _Float16 f16;
typedef _Float16 half8 __attribute__((ext_vector_type(8)));
typedef _Float16 half4v __attribute__((ext_vector_type(4)));
typedef __fp16 fp16x2 __attribute__((ext_vector_type(2)));
typedef float floatx4 __attribute__((ext_vector_type(4)));
typedef unsigned int uint;

constexpr int Bsz = 4, Tseq = 2048, Cdim = 1024, NH = 16, HDim = 64;
constexpr int Mtok = Bsz * Tseq;      // 8192
constexpr int N_QKV = 3 * Cdim;       // 3072
constexpr int NQT = Tseq / 64;        // 32 q-tiles
constexpr float QSCALE = 0.18033688f; // 0.125 * log2(e)

#define GLDS16(src, dst) __builtin_amdgcn_global_load_lds( \
    (const __attribute__((address_space(1))) void*)(src),  \
    (__attribute__((address_space(3))) void*)(dst), 16, 0, 0)

__device__ __forceinline__ float fexp2(float x) { return __builtin_amdgcn_exp2f(x); }
__device__ __forceinline__ uint pkrtz(float a, float b) {
  fp16x2 h = __builtin_amdgcn_cvt_pkrtz(a, b);
  return __builtin_bit_cast(uint, h);
}

// ---------------- f32 -> f16 conversion ----------------
__global__ void cvt_kernel(const float* __restrict__ in, f16* __restrict__ out, int n) {
  int i = (blockIdx.x * blockDim.x + threadIdx.x) * 4;
  if (i >= n) return;
  float4 v = *(const float4*)(in + i);
  half4v o;
  o[0] = (f16)v.x; o[1] = (f16)v.y; o[2] = (f16)v.z; o[3] = (f16)v.w;
  *(half4v*)(out + i) = o;
}

// ---------------- GEMM: C[m][n] = sum_k X[m][k] * W[n][k] ----------------
template<int EPI>
__global__ __launch_bounds__(256)
void gemm_kernel(const f16* __restrict__ X, const f16* __restrict__ W,
                 float* __restrict__ outF,
                 f16* __restrict__ q_out, f16* __restrict__ k_out, f16* __restrict__ v_out,
                 int M, int N, int K)
{
  constexpr int BM = 128, BN = 128, BK = 32;
  __shared__ __align__(16) f16 As[BM * BK];
  __shared__ __align__(16) f16 Bs[BN * BK];
  const int tid = threadIdx.x;
  const int wave = tid >> 6;
  const int lane = tid & 63;
  const int g = lane >> 4, lm = lane & 15;
  const int nbn = N / BN;
  const int bm = blockIdx.x / nbn;
  const int bn = blockIdx.x % nbn;
  const int m0 = bm * BM, n0 = bn * BN;
  const int wr = wave >> 1, wc = wave & 1;

  floatx4 acc[4][4];
#pragma unroll
  for (int i = 0; i < 4; ++i)
#pragma unroll
    for (int j = 0; j < 4; ++j) acc[i][j] = (floatx4)0.0f;

  for (int k0 = 0; k0 < K; k0 += BK) {
    __syncthreads();
#pragma unroll
    for (int t = 0; t < 2; ++t) {
      int row = (wave * 2 + t) * 16 + (lane >> 2);
      int cg = (lane & 3) ^ ((row >> 1) & 3);
      const f16* srcA = X + (size_t)(m0 + row) * K + k0 + cg * 8;
      GLDS16(srcA, (char*)As + (wave * 2 + t) * 1024);
      const f16* srcB = W + (size_t)(n0 + row) * K + k0 + cg * 8;
      GLDS16(srcB, (char*)Bs + (wave * 2 + t) * 1024);
    }
    __syncthreads();

    half8 af[4], bf[4];
#pragma unroll
    for (int i = 0; i < 4; ++i) {
      int rowa = wr * 64 + i * 16 + lm;
      int cga = g ^ ((rowa >> 1) & 3);
      af[i] = *(const half8*)((const char*)As + rowa * 64 + cga * 16);
      int rowb = wc * 64 + i * 16 + lm;
      int cgb = g ^ ((rowb >> 1) & 3);
      bf[i] = *(const half8*)((const char*)Bs + rowb * 64 + cgb * 16);
    }
#pragma unroll
    for (int i = 0; i < 4; ++i)
#pragma unroll
      for (int j = 0; j < 4; ++j)
        acc[i][j] = __builtin_amdgcn_mfma_f32_16x16x32_f16(af[i], bf[j], acc[i][j], 0, 0, 0);
  }

#pragma unroll
  for (int i = 0; i < 4; ++i) {
#pragma unroll
    for (int j = 0; j < 4; ++j) {
#pragma unroll
      for (int r = 0; r < 4; ++r) {
        int m = m0 + wr * 64 + i * 16 + 4 * g + r;
        int n = n0 + wc * 64 + j * 16 + lm;
        float v = acc[i][j][r];
        if constexpr (EPI == 1) {
          outF[(size_t)m * N + n] = v;
        } else {
          int which = n >> 10;
          int inner = n & 1023;
          int h = inner >> 6, hd = inner & 63;
          int b = m >> 11, t = m & 2047;
          if (which == 0) v *= QSCALE;  // fold softmax scale*log2e into Q
          f16* dst = which == 0 ? q_out : (which == 1 ? k_out : v_out);
          dst[(((size_t)(b * NH + h)) * Tseq + t) * HDim + hd] = (f16)v;
        }
      }
    }
  }
}

// ---------------- causal flash attention, paired q-tiles ----------------
__device__ __forceinline__ void commit_kv(char* kb, char* vbuf, int kr, int kc, int vkv, int vh0,
                                          half8 k0, half8 k1, half8 v0, half8 v1) {
  *(half8*)(kb + kr * 128 + 16 * ((2 * kc)     ^ (kr & 7))) = k0;
  *(half8*)(kb + kr * 128 + 16 * ((2 * kc + 1) ^ (kr & 7))) = k1;
#pragma unroll
  for (int i = 0; i < 8; ++i) {
    *(f16*)(vbuf + (vh0 + i)     * 128 + 16 * ((vkv >> 3) ^ i) + (vkv & 7) * 2) = v0[i];
    *(f16*)(vbuf + (vh0 + 8 + i) * 128 + 16 * ((vkv >> 3) ^ i) + (vkv & 7) * 2) = v1[i];
  }
}

__device__ __forceinline__ void softmax_tile(floatx4* s, float& m_run, float& l_run, floatx4* acc,
                                             bool diag, int j0, int qg, char* pwrow, int g, int lm) {
  if (diag) {
#pragma unroll
    for (int nf = 0; nf < 4; ++nf)
#pragma unroll
      for (int r = 0; r < 4; ++r)
        if (j0 + nf * 16 + 4 * g + r > qg) s[nf][r] = -1e30f;
  }
  float mx = -1e30f;
#pragma unroll
  for (int nf = 0; nf < 4; ++nf) {
    float a = fmaxf(fmaxf(s[nf][0], s[nf][1]), fmaxf(s[nf][2], s[nf][3]));
    mx = fmaxf(mx, a);
  }
  mx = fmaxf(mx, __shfl_xor(mx, 16, 64));
  mx = fmaxf(mx, __shfl_xor(mx, 32, 64));
  if (!__all(mx <= m_run + 8.0f)) {   // defer-max (T13)
    float nm = fmaxf(m_run, mx);
    float sc = fexp2(m_run - nm);
    m_run = nm;
    l_run *= sc;
    float s0 = __shfl(sc, 4 * g + 0, 64), s1 = __shfl(sc, 4 * g + 1, 64);
    float s2 = __shfl(sc, 4 * g + 2, 64), s3 = __shfl(sc, 4 * g + 3, 64);
#pragma unroll
    for (int ng = 0; ng < 4; ++ng) {
      acc[ng][0] *= s0; acc[ng][1] *= s1; acc[ng][2] *= s2; acc[ng][3] *= s3;
    }
  }
  float rs = 0.f;
#pragma unroll
  for (int nf = 0; nf < 4; ++nf) {
    float p0 = fexp2(s[nf][0] - m_run), p1 = fexp2(s[nf][1] - m_run);
    float p2 = fexp2(s[nf][2] - m_run), p3 = fexp2(s[nf][3] - m_run);
    rs += (p0 + p1) + (p2 + p3);
    uint lo = pkrtz(p0, p1), hi = pkrtz(p2, p3);
    int slot = 2 * nf + (g >> 1);
    uint2 u; u.x = lo; u.y = hi;
    *(uint2*)(pwrow + 16 * (slot ^ (lm & 7)) + 8 * (g & 1)) = u;
  }
  rs += __shfl_xor(rs, 16, 64);
  rs += __shfl_xor(rs, 32, 64);
  l_run += rs;
}

__device__ __forceinline__ void store_o(const floatx4* acc, float l, int q0w, int g, int lm,
                                        f16* __restrict__ Y, int b, int h) {
#pragma unroll
  for (int r = 0; r < 4; ++r) {
    float lq = __shfl(l, 4 * g + r, 64);
    float inv = 1.0f / lq;
    int t = q0w + 4 * g + r;
    size_t base = ((size_t)(b * Tseq + t)) * Cdim + h * HDim;
#pragma unroll
    for (int ng = 0; ng < 4; ++ng)
      Y[base + ng * 16 + lm] = (f16)(acc[ng][r] * inv);
  }
}

__global__ __launch_bounds__(256)
void attn_kernel(const f16* __restrict__ Q, const f16* __restrict__ Kg,
                 const f16* __restrict__ V, f16* __restrict__ Y)
{
  // LDS: K dbuf 2*8192 | V dbuf 2*8192 | Pw 4 waves * 2048  == 40960
  __shared__ __align__(16) char smem[40960];
  // XCD-locality remap: each XCD owns a contiguous bh range
  int wg = blockIdx.x;
  int lin = (wg & 7) * 128 + (wg >> 3);
  const int p  = lin & 15;
  const int bh = lin >> 4;
  const int qtA = p, qtB = NQT - 1 - p;
  const int ntB = NQT - p;
  const f16* Qb = Q + (size_t)bh * Tseq * HDim;
  const f16* Kb = Kg + (size_t)bh * Tseq * HDim;
  const f16* Vb = V + (size_t)bh * Tseq * HDim;

  const int tid = threadIdx.x, w = tid >> 6, lane = tid & 63;
  const int g = lane >> 4, lm = lane & 15;
  char* pwrow = smem + 32768 + w * 2048 + lm * 128;

  const int q0A = qtA * 64, q0B = qtB * 64;
  const int qgA = q0A + w * 16 + lm, qgB = q0B + w * 16 + lm;

  half8 qfA0 = *(const half8*)(Qb + (size_t)(q0A + w * 16 + lm) * HDim + g * 8);
  half8 qfA1 = *(const half8*)(Qb + (size_t)(q0A + w * 16 + lm) * HDim + 32 + g * 8);
  half8 qfB0 = *(const half8*)(Qb + (size_t)(q0B + w * 16 + lm) * HDim + g * 8);
  half8 qfB1 = *(const half8*)(Qb + (size_t)(q0B + w * 16 + lm) * HDim + 32 + g * 8);

  floatx4 accA[4], accB[4];
  float mA = -1e30f, lA = 0.f, mB = -1e30f, lB = 0.f;
#pragma unroll
  for (int ng = 0; ng < 4; ++ng) { accA[ng] = (floatx4)0.f; accB[ng] = (floatx4)0.f; }

  const int kr = tid >> 2, kc = tid & 3;
  const int vkv = tid & 63, vh0 = (tid >> 6) * 16;

  { // prologue: stage tile 0 into buffer 0
    const f16* kg = Kb + (size_t)kr * HDim + kc * 16;
    half8 k0 = *(const half8*)kg, k1 = *(const half8*)(kg + 8);
    const f16* vg = Vb + (size_t)vkv * HDim + vh0;
    half8 v0 = *(const half8*)vg, v1 = *(const half8*)(vg + 8);
    commit_kv(smem, smem + 16384, kr, kc, vkv, vh0, k0, k1, v0, v1);
  }
  __syncthreads();

  for (int jt = 0; jt < ntB; ++jt) {
    const int cur = jt & 1;
    const int j0 = jt * 64;
    const bool activeA = (jt <= p);
    const bool more = (jt + 1 < ntB);

    // stage tile jt+1 into the spare buffer NOW; staging regs die immediately.
    // buf[cur^1] was last read in iteration jt-1 (barrier since), so it's free.
    if (more) {
      const f16* kg = Kb + (size_t)(j0 + 64 + kr) * HDim + kc * 16;
      half8 k0 = *(const half8*)kg, k1 = *(const half8*)(kg + 8);
      const f16* vg = Vb + (size_t)(j0 + 64 + vkv) * HDim + vh0;
      half8 v0 = *(const half8*)vg, v1 = *(const half8*)(vg + 8);
      commit_kv(smem + (cur ^ 1) * 8192, smem + 16384 + (cur ^ 1) * 8192,
                kr, kc, vkv, vh0, k0, k1, v0, v1);
    }

    char* kb   = smem + cur * 8192;
    char* vbuf = smem + 16384 + cur * 8192;

    floatx4 sA[4], sB[4];
    if (activeA) {
#pragma unroll
      for (int nf = 0; nf < 4; ++nf) {
        half8 kf0 = *(const half8*)(kb + (nf * 16 + lm) * 128 + 16 * ((g)     ^ (lm & 7)));
        half8 kf1 = *(const half8*)(kb + (nf * 16 + lm) * 128 + 16 * ((4 + g) ^ (lm & 7)));
        sB[nf] = __builtin_amdgcn_mfma_f32_16x16x32_f16(kf0, qfB0, (floatx4)0.f, 0, 0, 0);
        sB[nf] = __builtin_amdgcn_mfma_f32_16x16x32_f16(kf1, qfB1, sB[nf], 0, 0, 0);
        sA[nf] = __builtin_amdgcn_mfma_f32_16x16x32_f16(kf0, qfA0, (floatx4)0.f, 0, 0, 0);
        sA[nf] = __builtin_amdgcn_mfma_f32_16x16x32_f16(kf1, qfA1, sA[nf], 0, 0, 0);
      }
    } else {
#pragma unroll
      for (int nf = 0; nf < 4; ++nf) {
        half8 kf0 = *(const half8*)(kb + (nf * 16 + lm) * 128 + 16 * ((g)     ^ (lm & 7)));
        half8 kf1 = *(const half8*)(kb + (nf * 16 + lm) * 128 + 16 * ((4 + g) ^ (lm & 7)));
        sB[nf] = __builtin_amdgcn_mfma_f32_16x16x32_f16(kf0, qfB0, (floatx4)0.f, 0, 0, 0);
        sB[nf] = __builtin_amdgcn_mfma_f32_16x16x32_f16(kf1, qfB1, sB[nf], 0, 0, 0);
      }
    }

    softmax_tile(sB, mB, lB, accB, jt == qtB, j0, qgB, pwrow, g, lm);
    half8 paB0 = *(const half8*)(pwrow + 16 * ((g)     ^ (lm & 7)));
    half8 paB1 = *(const half8*)(pwrow + 16 * ((4 + g) ^ (lm & 7)));
    half8 paA0 = paB0, paA1 = paB1;
    if (activeA) {
      softmax_tile(sA, mA, lA, accA, jt == qtA, j0, qgA, pwrow, g, lm);
      paA0 = *(const half8*)(pwrow + 16 * ((g)     ^ (lm & 7)));
      paA1 = *(const half8*)(pwrow + 16 * ((4 + g) ^ (lm & 7)));
    }

    if (activeA) {
#pragma unroll
      for (int c = 0; c < 2; ++c)
#pragma unroll
        for (int ng = 0; ng < 4; ++ng) {
          half8 vbf = *(const half8*)(vbuf + (ng * 16 + lm) * 128 + 16 * ((4 * c + g) ^ (lm & 7)));
          accB[ng] = __builtin_amdgcn_mfma_f32_16x16x32_f16(c ? paB1 : paB0, vbf, accB[ng], 0, 0, 0);
          accA[ng] = __builtin_amdgcn_mfma_f32_16x16x32_f16(c ? paA1 : paA0, vbf, accA[ng], 0, 0, 0);
        }
    } else {
#pragma unroll
      for (int c = 0; c < 2; ++c)
#pragma unroll
        for (int ng = 0; ng < 4; ++ng) {
          half8 vbf = *(const half8*)(vbuf + (ng * 16 + lm) * 128 + 16 * ((4 * c + g) ^ (lm & 7)));
          accB[ng] = __builtin_amdgcn_mfma_f32_16x16x32_f16(c ? paB1 : paB0, vbf, accB[ng], 0, 0, 0);
        }
    }

    __syncthreads();
  }

  const int b = bh >> 4, h = bh & 15;
  store_o(accA, lA, q0A + 16 * w, g, lm, Y, b, h);
  store_o(accB, lB, q0B + 16 * w, g, lm, Y, b, h);
}

// ---------------- launcher ----------------
extern "C" void kernel_launch(void* const* d_in, const int* in_sizes, int n_in,
                              void* d_out, int out_size, void* d_ws, size_t ws_size,
                              hipStream_t stream)
{
  const float* x      = (const float*)d_in[0];
  const float* W_attn = (const float*)d_in[1];
  const float* W_proj = (const float*)d_in[2];
  float* out = (float*)d_out;

  char* ws = (char*)d_ws;
  f16* xh  = (f16*)(ws);
  f16* wAh = (f16*)(ws + (size_t)(16u << 20));
  f16* wPh = (f16*)(ws + (size_t)(22u << 20));
  f16* Qh  = (f16*)(ws + (size_t)(24u << 20));
  f16* Kh  = (f16*)(ws + (size_t)(40u << 20));
  f16* Vh  = (f16*)(ws + (size_t)(56u << 20));
  f16* yh  = xh;

  const int nx  = Mtok * Cdim;
  const int nwa = N_QKV * Cdim;
  const int nwp = Cdim * Cdim;
  cvt_kernel<<<(nx / 4 + 255) / 256, 256, 0, stream>>>(x, xh, nx);
  cvt_kernel<<<(nwa / 4 + 255) / 256, 256, 0, stream>>>(W_attn, wAh, nwa);
  cvt_kernel<<<(nwp / 4 + 255) / 256, 256, 0, stream>>>(W_proj, wPh, nwp);

  gemm_kernel<0><<<dim3((Mtok / 128) * (N_QKV / 128)), 256, 0, stream>>>(
      xh, wAh, nullptr, Qh, Kh, Vh, Mtok, N_QKV, Cdim);

  attn_kernel<<<dim3(1024), 256, 0, stream>>>(Qh, Kh, Vh, yh);

  gemm_kernel<1><<<dim3((Mtok / 128) * (Cdim / 128)), 256, 0, stream>>>(
      yh, wPh, out, nullptr, nullptr, nullptr, Mtok, Cdim, Cdim);
}